// Round 1
// baseline (7810.442 us; speedup 1.0000x reference)
//
#include <hip/hip_runtime.h>

// GRUNet: 2-layer GRU (B=128, T=512, I=64, H=256) + ReLU + FC(256->2).
// Round 1: correctness-first fp32 baseline.
//   - One kernel launch per macro-step s in [0, 512]:
//       layer0 computes t = s      (if s < T)
//       layer1 computes t = s - 1  (if s >= 1)   [software pipeline]
//     Kernel boundaries provide all cross-step synchronization.
//   - Grid = 256 WGs (128 per layer), 256 threads each; per-WG tile:
//     BT=32 batch rows x JT=8 hidden units; 24 weight rows staged in LDS
//     (~50 KB dynamic LDS), h-state double-buffered in d_ws.

namespace {
constexpr int kB = 128;   // batch
constexpr int kT = 512;   // timesteps
constexpr int kI = 64;    // layer0 input dim
constexpr int kH = 256;   // hidden dim

constexpr int BT = 32;                 // batch rows per WG
constexpr int JT = 8;                  // hidden units per WG
constexpr int PH = 260;                // padded LDS stride for 256-wide rows (bank-conflict-free, 16B aligned)
constexpr int PX = 68;                 // padded LDS stride for 64-wide rows
constexpr int NB = kB / BT;            // 4 batch tiles
constexpr int NJ = kH / JT;            // 32 hidden tiles
constexpr int WPL = NB * NJ;           // 128 workgroups per layer

constexpr int kLdsFloats = 3 * JT * (PH + PH);     // worst case (layer1): 24*(260+260)
constexpr size_t kLdsBytes = (size_t)kLdsFloats * 4; // 49920 B  (< 64 KB)
}

__device__ __forceinline__ float sigf(float v) { return 1.0f / (1.0f + expf(-v)); }

__global__ __launch_bounds__(256, 1) void gru_step(
    const float* __restrict__ x,
    const float* __restrict__ wih0, const float* __restrict__ whh0,
    const float* __restrict__ bih0, const float* __restrict__ bhh0,
    const float* __restrict__ wih1, const float* __restrict__ whh1,
    const float* __restrict__ bih1, const float* __restrict__ bhh1,
    float* __restrict__ h0buf,      // [2][B][H] double-buffered layer0 hidden
    float* __restrict__ h1buf,      // [2][B][H] double-buffered layer1 hidden
    int s)
{
  const int bid   = blockIdx.x;
  const int layer = bid >> 7;          // 0..1
  const int wid   = bid & (WPL - 1);   // 0..127
  const int tid   = threadIdx.x;

  if (layer == 0) { if (s >= kT) return; }
  else            { if (s <  1 ) return; }
  const int t = (layer == 0) ? s : (s - 1);

  const int b0 = (wid & (NB - 1)) * BT;   // batch tile base
  const int j0 = (wid >> 2) * JT;         // hidden tile base

  const float* __restrict__ win = (layer == 0) ? wih0 : wih1;
  const float* __restrict__ whh = (layer == 0) ? whh0 : whh1;
  const float* __restrict__ bih = (layer == 0) ? bih0 : bih1;
  const float* __restrict__ bhh = (layer == 0) ? bhh0 : bhh1;
  const int idim = (layer == 0) ? kI : kH;
  const int ipad = (layer == 0) ? PX : PH;

  // Input sequence row pointers for this step.
  const float* __restrict__ invec;
  int instride;
  if (layer == 0) { invec = x + (size_t)t * kI;                  instride = kT * kI; }
  else            { invec = h0buf + (size_t)(t & 1) * kB * kH;   instride = kH;      }

  const float* __restrict__ hprev = (layer == 0)
      ? (h0buf + (size_t)((s + 1) & 1) * kB * kH)     // h0(t-1)
      : (h1buf + (size_t)(s & 1) * kB * kH);          // h1(t-1)
  float* __restrict__ hout = (layer == 0)
      ? (h0buf + (size_t)(s & 1) * kB * kH)           // h0(t)
      : (h1buf + (size_t)((s - 1) & 1) * kB * kH);    // h1(t)

  // ---- stage this WG's 24 weight rows (gate-major: r,z,n) into LDS ----
  extern __shared__ float lds[];
  float* w_in = lds;                       // [3*JT][ipad]
  float* w_h  = w_in + 3 * JT * ipad;      // [3*JT][PH]
  {
    const int pr = idim / 4;
    for (int i = tid; i < 3 * JT * pr; i += 256) {
      const int r = i / pr, c = (i - r * pr) * 4;
      const int g = r / JT, jr = r - g * JT;
      *(float4*)(w_in + r * ipad + c) =
          *(const float4*)(win + (size_t)(g * kH + j0 + jr) * idim + c);
    }
    const int ph = kH / 4;
    for (int i = tid; i < 3 * JT * ph; i += 256) {
      const int r = i / ph, c = (i - r * ph) * 4;
      const int g = r / JT, jr = r - g * JT;
      *(float4*)(w_h + r * PH + c) =
          *(const float4*)(whh + (size_t)(g * kH + j0 + jr) * kH + c);
    }
  }
  __syncthreads();

  // ---- compute: thread = (jj, b) ----
  const int jj = tid & (JT - 1);
  const int b  = tid >> 3;                 // 0..31
  const int j  = j0 + jj;                  // global hidden index

  const float* __restrict__ arow = invec + (size_t)(b0 + b) * instride;
  const float* __restrict__ hrow = hprev + (size_t)(b0 + b) * kH;

  float xr = 0.f, xz = 0.f, xn = 0.f;
  #pragma unroll 4
  for (int k = 0; k < idim; k += 4) {
    const float4 iv = *(const float4*)(arow + k);
    const float4 wr = *(const float4*)(w_in + (0 * JT + jj) * ipad + k);
    const float4 wz = *(const float4*)(w_in + (1 * JT + jj) * ipad + k);
    const float4 wn = *(const float4*)(w_in + (2 * JT + jj) * ipad + k);
    xr += iv.x * wr.x + iv.y * wr.y + iv.z * wr.z + iv.w * wr.w;
    xz += iv.x * wz.x + iv.y * wz.y + iv.z * wz.z + iv.w * wz.w;
    xn += iv.x * wn.x + iv.y * wn.y + iv.z * wn.z + iv.w * wn.w;
  }
  float hr = 0.f, hz = 0.f, hn = 0.f;
  #pragma unroll 4
  for (int k = 0; k < kH; k += 4) {
    const float4 hv = *(const float4*)(hrow + k);
    const float4 wr = *(const float4*)(w_h + (0 * JT + jj) * PH + k);
    const float4 wz = *(const float4*)(w_h + (1 * JT + jj) * PH + k);
    const float4 wn = *(const float4*)(w_h + (2 * JT + jj) * PH + k);
    hr += hv.x * wr.x + hv.y * wr.y + hv.z * wr.z + hv.w * wr.w;
    hz += hv.x * wz.x + hv.y * wz.y + hv.z * wz.z + hv.w * wz.w;
    hn += hv.x * wn.x + hv.y * wn.y + hv.z * wn.z + hv.w * wn.w;
  }

  // PyTorch gate order r,z,n:  n = tanh(xn + b_ihn + r*(hn + b_hhn))
  const float rr = sigf(xr + hr + bih[j] + bhh[j]);
  const float zz = sigf(xz + hz + bih[kH + j] + bhh[kH + j]);
  const float nn = tanhf(xn + bih[2 * kH + j] + rr * (hn + bhh[2 * kH + j]));
  const float hp = hrow[j];
  hout[(size_t)(b0 + b) * kH + j] = (1.f - zz) * nn + zz * hp;
}

// out[b][o] = fc_b[o] + sum_k relu(h1_final[b][k]) * fc_w[o][k]
__global__ __launch_bounds__(256, 1) void gru_fc(
    const float* __restrict__ h1buf,
    const float* __restrict__ fcw, const float* __restrict__ fcb,
    float* __restrict__ out)
{
  const int tid = threadIdx.x;
  const int o = tid & 1;          // 0..1
  const int b = tid >> 1;         // 0..127
  // h1(T-1) lives at parity (T-1)&1 == 1
  const float* __restrict__ hf = h1buf + (size_t)1 * kB * kH + (size_t)b * kH;
  const float* __restrict__ wr = fcw + (size_t)o * kH;
  float acc = fcb[o];
  #pragma unroll 4
  for (int k = 0; k < kH; k += 4) {
    const float4 hv = *(const float4*)(hf + k);
    const float4 wv = *(const float4*)(wr + k);
    acc += fmaxf(hv.x, 0.f) * wv.x + fmaxf(hv.y, 0.f) * wv.y +
           fmaxf(hv.z, 0.f) * wv.z + fmaxf(hv.w, 0.f) * wv.w;
  }
  out[b * 2 + o] = acc;
}

extern "C" void kernel_launch(void* const* d_in, const int* in_sizes, int n_in,
                              void* d_out, int out_size, void* d_ws, size_t ws_size,
                              hipStream_t stream) {
  const float* x    = (const float*)d_in[0];
  const float* wih0 = (const float*)d_in[1];
  const float* whh0 = (const float*)d_in[2];
  const float* bih0 = (const float*)d_in[3];
  const float* bhh0 = (const float*)d_in[4];
  const float* wih1 = (const float*)d_in[5];
  const float* whh1 = (const float*)d_in[6];
  const float* bih1 = (const float*)d_in[7];
  const float* bhh1 = (const float*)d_in[8];
  const float* fcw  = (const float*)d_in[9];
  const float* fcb  = (const float*)d_in[10];

  float* h0buf = (float*)d_ws;                       // [2][B][H]
  float* h1buf = h0buf + 2 * kB * kH;                // [2][B][H]

  // zero both double-buffers (parity-1 slots must start as h(-1)=0)
  hipMemsetAsync(d_ws, 0, (size_t)4 * kB * kH * sizeof(float), stream);

  for (int s = 0; s <= kT; ++s) {
    gru_step<<<2 * WPL, 256, kLdsBytes, stream>>>(
        x, wih0, whh0, bih0, bhh0, wih1, whh1, bih1, bhh1, h0buf, h1buf, s);
  }
  gru_fc<<<1, 256, 0, stream>>>(h1buf, fcw, fcb, (float*)d_out);
}